// Round 5
// baseline (4065.685 us; speedup 1.0000x reference)
//
#include <hip/hip_runtime.h>
#include <stdint.h>

// ---------- types / helpers ----------
typedef __attribute__((ext_vector_type(8))) short short8;   // 8 bf16 in 4 VGPRs
typedef __attribute__((ext_vector_type(4))) float f32x4;

__device__ __forceinline__ unsigned short f32_to_bf16(float f) {
    unsigned int u = __float_as_uint(f);
    unsigned int r = (u + 0x7FFF + ((u >> 16) & 1)) >> 16;   // RNE
    return (unsigned short)r;
}
__device__ __forceinline__ float bf16_to_f32(unsigned short s) {
    return __uint_as_float(((unsigned int)s) << 16);
}

// ---------- prep kernels ----------
__global__ void cvt_bf16_kernel(const float* __restrict__ in,
                                unsigned short* __restrict__ out, int n) {
    int i = (blockIdx.x * blockDim.x + threadIdx.x) * 4;
    if (i >= n) return;
    float4 v = *(const float4*)(in + i);
    ushort4 o;
    o.x = f32_to_bf16(v.x);
    o.y = f32_to_bf16(v.y);
    o.z = f32_to_bf16(v.z);
    o.w = f32_to_bf16(v.w);
    *(ushort4*)(out + i) = o;
}

__global__ void bias_add_kernel(const float* __restrict__ bi,
                                const float* __restrict__ bh,
                                float* __restrict__ bias) {
    int i = blockIdx.x * blockDim.x + threadIdx.x;  // 4096
    bias[i] = bi[i] + bh[i];
}

__global__ void zero_kernel(unsigned int* __restrict__ p, int n) {
    int i = blockIdx.x * blockDim.x + threadIdx.x;
    if (i < n) p[i] = 0u;
}

// ---------- phase 1: xg[r][g] = bf16( x[r][:]·W_ih[g][:] + bias[g] ), r=b*512+t ----------
#define LDP 40  // padded LDS row pitch (shorts): 2-way conflicts only (free)

__global__ __launch_bounds__(256) void gemm_xproj(
    const unsigned short* __restrict__ A,   // x bf16 [16384][1024]
    const unsigned short* __restrict__ B,   // W_ih bf16 [4096][1024]
    const float* __restrict__ bias,         // [4096]
    unsigned short* __restrict__ C) {       // xg bf16 [16384][4096]
    __shared__ unsigned short As[64][LDP];
    __shared__ unsigned short Bs[64][LDP];
    const int tid  = threadIdx.x;
    const int lane = tid & 63;
    const int wave = tid >> 6;
    const int m0 = blockIdx.y * 64;
    const int n0 = blockIdx.x * 64;
    const int wm = (wave & 1) * 32;
    const int wn = (wave >> 1) * 32;

    f32x4 acc[2][2] = {};

    const int sr = tid >> 2;
    const int sk = (tid & 3) * 8;
    const int fr = lane & 15;
    const int fk = (lane >> 4) * 8;

    for (int k0 = 0; k0 < 1024; k0 += 32) {
        uint4 av = *(const uint4*)&A[(m0 + sr) * 1024 + k0 + sk];
        uint4 bv = *(const uint4*)&B[(n0 + sr) * 1024 + k0 + sk];
        __syncthreads();
        *(uint4*)&As[sr][sk] = av;
        *(uint4*)&Bs[sr][sk] = bv;
        __syncthreads();
        short8 a0 = *(const short8*)&As[wm + fr][fk];
        short8 a1 = *(const short8*)&As[wm + 16 + fr][fk];
        short8 b0 = *(const short8*)&Bs[wn + fr][fk];
        short8 b1 = *(const short8*)&Bs[wn + 16 + fr][fk];
        acc[0][0] = __builtin_amdgcn_mfma_f32_16x16x32_bf16(a0, b0, acc[0][0], 0, 0, 0);
        acc[0][1] = __builtin_amdgcn_mfma_f32_16x16x32_bf16(a0, b1, acc[0][1], 0, 0, 0);
        acc[1][0] = __builtin_amdgcn_mfma_f32_16x16x32_bf16(a1, b0, acc[1][0], 0, 0, 0);
        acc[1][1] = __builtin_amdgcn_mfma_f32_16x16x32_bf16(a1, b1, acc[1][1], 0, 0, 0);
    }

    const int col = lane & 15;
    const int rq  = (lane >> 4) * 4;
    for (int mt = 0; mt < 2; mt++) {
        for (int nt = 0; nt < 2; nt++) {
            int gcol = n0 + wn + nt * 16 + col;
            float bv = bias[gcol];
            for (int r = 0; r < 4; r++) {
                int grow = m0 + wm + mt * 16 + rq + r;
                C[(size_t)grow * 4096 + gcol] = f32_to_bf16(acc[mt][nt][r] + bv);
            }
        }
    }
}

// ---------- phase 2: persistent recurrence ----------
// 256 blocks x 512 threads, 1 block/CU. Block bid owns hidden units j0=4*bid..+3.
// W_hh slice in LDS as bf16 A-fragments (32 KB, staged once).
// h state: PLAIN bf16 [32][1024] double-buffered. B-fragment of lane (col,quad)
// = 16 consecutive bf16 at h[nt*16+col][k..k+7] -> aligned dwordx4 sc1 loads.
// Publish: epilogue threads store their own h (global_store_short sc1) + per-wave
// vmcnt drain; flag after __syncthreads. Poll: wave 7 only, lane i dwordx4-reads
// flags[4i..4i+3], __ballot all-set. All cross-block traffic raw sc0/sc1 (LLC),
// never compiler atomics (round-3 buffer_inv storm).
__global__ __launch_bounds__(512, 4) void lstm_persist(
    const float* __restrict__ Whh,          // [4096][1024] fp32
    const unsigned short* __restrict__ xg,  // bf16 [16384][4096], bias folded
    const float* __restrict__ c0,           // [32][1024] fp32
    unsigned short* __restrict__ hA,        // bf16 [32][1024], holds h(0) at entry
    unsigned short* __restrict__ hB,        // bf16 [32][1024]
    unsigned int* __restrict__ flags,       // [512][256]
    float* __restrict__ out) {              // [32][1024] fp32
    __shared__ unsigned short Afrag[16384];     // 32 KB
    __shared__ float partial[8][16][16];        // 8 KB  [wave][m][n_local]

    const int tid  = threadIdx.x;
    const int bid  = blockIdx.x;
    const int j0   = bid * 4;
    const int lane = tid & 63;
    const int wave = tid >> 6;
    const int ks   = wave >> 1;   // K-split 0..3 (256 k each)
    const int nt   = wave & 1;    // n-tile (batch 0-15 / 16-31)
    const int col  = lane & 15;
    const int quad = lane >> 4;

    // ---- stage W_hh slice -> A-fragment order (once) ----
    // chunk c: kq = c>>4 (k-octet), m = c&15 (m = q*4 + jj)
    for (int c = tid; c < 2048; c += 512) {
        int kq = c >> 4, m = c & 15;
        int q = m >> 2, jj = m & 3;
        const float* wr = Whh + (size_t)(q * 1024 + j0 + jj) * 1024 + kq * 8;
        float4 wa = *(const float4*)wr;
        float4 wb = *(const float4*)(wr + 4);
        short8 v;
        v[0] = f32_to_bf16(wa.x); v[1] = f32_to_bf16(wa.y);
        v[2] = f32_to_bf16(wa.z); v[3] = f32_to_bf16(wa.w);
        v[4] = f32_to_bf16(wb.x); v[5] = f32_to_bf16(wb.y);
        v[6] = f32_to_bf16(wb.z); v[7] = f32_to_bf16(wb.w);
        *(short8*)&Afrag[c * 8] = v;
    }

    const int ejj = (tid >> 5) & 3;  // epilogue ids (valid for tid<128)
    const int eb  = tid & 31;
    float cst = 0.f;
    float xz0 = 0.f, xz1 = 0.f, xz2 = 0.f, xz3 = 0.f;
    if (tid < 128) {
        cst = c0[eb * 1024 + j0 + ejj];
        // prefetch xg for t=0
        const unsigned short* p = xg + (size_t)(eb * 512) * 4096 + j0 + ejj;
        xz0 = bf16_to_f32(p[0]);
        xz1 = bf16_to_f32(p[1024]);
        xz2 = bf16_to_f32(p[2048]);
        xz3 = bf16_to_f32(p[3072]);
    }
    __syncthreads();

    // per-lane B-fragment base offset within an h buffer (elements)
    const int hoff = (nt * 16 + col) * 1024 + ks * 256 + quad * 8;

    for (int t = 0; t < 512; ++t) {
        const unsigned short* hR = (t & 1) ? hB : hA;
        unsigned short*       hW = (t & 1) ? hA : hB;

        // B-fragments: 8 aligned dwordx4 LLC loads, one drain
        const unsigned short* hb = hR + hoff;
        uint4 bv0, bv1, bv2, bv3, bv4, bv5, bv6, bv7;
        asm volatile("global_load_dwordx4 %0, %1, off sc1"            : "=v"(bv0) : "v"(hb) : "memory");
        asm volatile("global_load_dwordx4 %0, %1, off offset:64 sc1"  : "=v"(bv1) : "v"(hb) : "memory");
        asm volatile("global_load_dwordx4 %0, %1, off offset:128 sc1" : "=v"(bv2) : "v"(hb) : "memory");
        asm volatile("global_load_dwordx4 %0, %1, off offset:192 sc1" : "=v"(bv3) : "v"(hb) : "memory");
        asm volatile("global_load_dwordx4 %0, %1, off offset:256 sc1" : "=v"(bv4) : "v"(hb) : "memory");
        asm volatile("global_load_dwordx4 %0, %1, off offset:320 sc1" : "=v"(bv5) : "v"(hb) : "memory");
        asm volatile("global_load_dwordx4 %0, %1, off offset:384 sc1" : "=v"(bv6) : "v"(hb) : "memory");
        asm volatile("global_load_dwordx4 %0, %1, off offset:448 sc1" : "=v"(bv7) : "v"(hb) : "memory");
        asm volatile("s_waitcnt vmcnt(0)" ::: "memory");

        uint4 bvs[8] = {bv0, bv1, bv2, bv3, bv4, bv5, bv6, bv7};
        f32x4 acc = {0.f, 0.f, 0.f, 0.f};
#pragma unroll
        for (int u = 0; u < 8; ++u) {
            int kc = ks * 8 + u;
            short8 af = *(const short8*)&Afrag[((kc * 4 + quad) * 16 + col) * 8];
            union { uint4 u4; short8 s8; } cv;
            cv.u4 = bvs[u];
            acc = __builtin_amdgcn_mfma_f32_16x16x32_bf16(af, cv.s8, acc, 0, 0, 0);
        }
#pragma unroll
        for (int r = 0; r < 4; ++r) partial[wave][quad * 4 + r][col] = acc[r];
        __syncthreads();

        if (tid < 128) {
            const int ntb = eb >> 4, nl = eb & 15;
            float z[4];
#pragma unroll
            for (int q = 0; q < 4; ++q) {
                int m = q * 4 + ejj;
                z[q] = partial[0 + ntb][m][nl] + partial[2 + ntb][m][nl] +
                       partial[4 + ntb][m][nl] + partial[6 + ntb][m][nl];
            }
            z[0] += xz0; z[1] += xz1; z[2] += xz2; z[3] += xz3;
            float ig = 1.f / (1.f + __expf(-z[0]));
            float fg = 1.f / (1.f + __expf(-z[1]));
            float gg = tanhf(z[2]);
            float og = 1.f / (1.f + __expf(-z[3]));
            cst = fg * cst + ig * gg;
            float hn = og * tanhf(cst);
            if (t < 511) {
                // direct h publish (2B LLC store), then per-wave drain
                unsigned int hb16 = f32_to_bf16(hn);
                unsigned short* hp = hW + eb * 1024 + j0 + ejj;
                asm volatile("global_store_short %0, %1, off sc1"
                             :: "v"(hp), "v"(hb16) : "memory");
                asm volatile("s_waitcnt vmcnt(0)" ::: "memory");
                // prefetch xg for t+1 (completes during barrier; no wait here)
                const unsigned short* p = xg + (size_t)(eb * 512 + t + 1) * 4096 + j0 + ejj;
                xz0 = bf16_to_f32(p[0]);
                xz1 = bf16_to_f32(p[1024]);
                xz2 = bf16_to_f32(p[2048]);
                xz3 = bf16_to_f32(p[3072]);
            } else {
                out[eb * 1024 + j0 + ejj] = hn;  // final output
            }
        }
        if (t == 511) break;  // uniform
        __syncthreads();      // all h stores drained (waves 0-1 drained above)

        // barrier arrive: plain LLC store of 1
        if (tid == 0) {
            unsigned int one = 1u;
            asm volatile("global_store_dword %0, %1, off sc0 sc1"
                         :: "v"(flags + (size_t)t * 256 + bid), "v"(one) : "memory");
        }
        // barrier wait: wave 7 only; lane i covers flags[4i..4i+3]
        if (wave == 7) {
            const unsigned int* fp = flags + (size_t)t * 256 + lane * 4;
            while (true) {
                uint4 v;
                asm volatile("global_load_dwordx4 %0, %1, off sc0 sc1\n\ts_waitcnt vmcnt(0)"
                             : "=v"(v) : "v"(fp) : "memory");
                if (__ballot((v.x & v.y & v.z & v.w) != 0u) == ~0ull) break;
            }
        }
        __syncthreads();
    }
}

// ---------- launch ----------
extern "C" void kernel_launch(void* const* d_in, const int* in_sizes, int n_in,
                              void* d_out, int out_size, void* d_ws, size_t ws_size,
                              hipStream_t stream) {
    const float* x    = (const float*)d_in[0];  // [32][512][1024]
    const float* h0   = (const float*)d_in[1];  // [32][1024]
    const float* c0   = (const float*)d_in[2];  // [32][1024]
    const float* Wih  = (const float*)d_in[3];  // [4096][1024]
    const float* Whh  = (const float*)d_in[4];  // [4096][1024]
    const float* b_ih = (const float*)d_in[5];  // [4096]
    const float* b_hh = (const float*)d_in[6];  // [4096]
    float* out = (float*)d_out;
    char* ws = (char*)d_ws;

    // workspace layout (within round-2-proven 176,439,296 B):
    //   xg    @ 0          134217728 B (bf16, live through persistent phase)
    //   xA    @ 134217728   33554432 B (bf16 x; DEAD after gemm -> flags overlay)
    //   wB    @ 167772160    8388608 B (bf16 W_ih)
    //   bias  @ 176160768      16384 B
    //   hA    @ 176177152      65536 B (bf16 [32][1024])
    //   hB    @ 176242688      65536 B
    unsigned short* xg   = (unsigned short*)(ws);
    unsigned short* xA   = (unsigned short*)(ws + 134217728);
    unsigned short* wB   = (unsigned short*)(ws + 167772160);
    float*          bias = (float*)(ws + 176160768);
    unsigned short* hA   = (unsigned short*)(ws + 176177152);
    unsigned short* hB   = (unsigned short*)(ws + 176242688);
    unsigned int*   flags = (unsigned int*)(ws + 134217728);  // overlays xA after gemm

    cvt_bf16_kernel<<<16384, 256, 0, stream>>>(x, xA, 16777216);
    cvt_bf16_kernel<<<4096, 256, 0, stream>>>(Wih, wB, 4194304);
    bias_add_kernel<<<16, 256, 0, stream>>>(b_ih, b_hh, bias);

    dim3 g1(64, 256);
    gemm_xproj<<<g1, 256, 0, stream>>>(xA, wB, bias, xg);

    // xA dead from here; reuse as flag storage
    zero_kernel<<<512, 256, 0, stream>>>(flags, 512 * 256);
    // h(0): plain bf16 [b][j]
    cvt_bf16_kernel<<<32, 256, 0, stream>>>(h0, hA, 32768);

    lstm_persist<<<256, 512, 0, stream>>>(Whh, xg, c0, hA, hB, flags, out);
}